// Round 2
// baseline (288.374 us; speedup 1.0000x reference)
//
#include <hip/hip_runtime.h>
#include <hip/hip_bf16.h>
#include <stdint.h>

#define BATCH 512
#define NUM_CLASSES 100000
#define NVEC (NUM_CLASSES / 4)     // 25000 float4 per row
#define BLOCK 512

// cos(0.5), sin(0.5) as literals (margin = 0.5)
#define COS_M 0.8775825618903728f
#define SIN_M 0.479425538604203f
#define SHIFT 64.0f                // fixed logsumexp shift; logits bounded by 63.36
#define MAGIC 0x5A5A5A5Au          // != harness poison 0xAAAAAAAA

__device__ __forceinline__ float block_reduce_sum(float v) {
    // wave-64 shuffle reduce
    #pragma unroll
    for (int off = 32; off > 0; off >>= 1)
        v += __shfl_down(v, off, 64);
    __shared__ float smem[BLOCK / 64];
    const int lane = threadIdx.x & 63;
    const int wid  = threadIdx.x >> 6;
    if (lane == 0) smem[wid] = v;
    __syncthreads();
    if (wid == 0) {
        v = (lane < (BLOCK / 64)) ? smem[lane] : 0.0f;
        #pragma unroll
        for (int off = 4; off > 0; off >>= 1)
            v += __shfl_down(v, off, 64);
    }
    return v;   // valid in thread 0
}

__global__ __launch_bounds__(BLOCK)
void arc_fused(const float* __restrict__ costh,
               const int*   __restrict__ label,
               float*       __restrict__ out,
               unsigned long long* __restrict__ slot) {   // d_ws, 512 qwords
    const int row = blockIdx.x;
    const float* rp = costh + (size_t)row * NUM_CLASSES;
    const float4* vp = (const float4*)rp;

    // 2x unrolled, independent accumulators for deeper MLP
    float s0 = 0.0f, s1 = 0.0f;
    int i = threadIdx.x;
    for (; i + BLOCK < NVEC; i += 2 * BLOCK) {
        float4 a = vp[i];
        float4 b = vp[i + BLOCK];
        s0 += __expf(fmaf(64.0f, a.x, -SHIFT)) + __expf(fmaf(64.0f, a.y, -SHIFT))
            + __expf(fmaf(64.0f, a.z, -SHIFT)) + __expf(fmaf(64.0f, a.w, -SHIFT));
        s1 += __expf(fmaf(64.0f, b.x, -SHIFT)) + __expf(fmaf(64.0f, b.y, -SHIFT))
            + __expf(fmaf(64.0f, b.z, -SHIFT)) + __expf(fmaf(64.0f, b.w, -SHIFT));
    }
    if (i < NVEC) {
        float4 a = vp[i];
        s0 += __expf(fmaf(64.0f, a.x, -SHIFT)) + __expf(fmaf(64.0f, a.y, -SHIFT))
            + __expf(fmaf(64.0f, a.z, -SHIFT)) + __expf(fmaf(64.0f, a.w, -SHIFT));
    }

    float tot = block_reduce_sum(s0 + s1);

    if (threadIdx.x == 0) {
        const int lab = label[row];
        const float c_y = rp[lab];
        // cos(acos(c) + m) = c*cos(m) - sqrt(1-c^2)*sin(m)
        const float t = 64.0f * (c_y * COS_M -
                                 sqrtf(fmaxf(0.0f, 1.0f - c_y * c_y)) * SIN_M);
        // swap the raw label logit for the margin-shifted one
        const float s = tot - __expf(fmaf(64.0f, c_y, -SHIFT)) + __expf(t - SHIFT);
        // (lse - target_logit) / BATCH, published with a release store + MAGIC tag
        const float part = ((SHIFT + logf(s)) - t) * (1.0f / (float)BATCH);
        const unsigned long long w =
            ((unsigned long long)MAGIC << 32) | (unsigned long long)__float_as_uint(part);
        __hip_atomic_store(&slot[row], w, __ATOMIC_RELEASE, __HIP_MEMORY_SCOPE_AGENT);
    }

    // Block 0 finalizes: each thread waits for its row's slot, then block-reduce.
    // 512 blocks x 8 waves = 4096 waves << 8192 wave slots, so all blocks get
    // dispatched while block 0 spins — no co-residency deadlock.
    if (blockIdx.x == 0) {
        unsigned long long w;
        do {
            w = __hip_atomic_load(&slot[threadIdx.x], __ATOMIC_ACQUIRE,
                                  __HIP_MEMORY_SCOPE_AGENT);
        } while ((unsigned)(w >> 32) != MAGIC);
        __syncthreads();   // protect shared smem reuse between the two reductions
        float v = __uint_as_float((unsigned)(w & 0xFFFFFFFFu));
        float tot2 = block_reduce_sum(v);
        if (threadIdx.x == 0)
            out[0] = tot2;
    }
}

extern "C" void kernel_launch(void* const* d_in, const int* in_sizes, int n_in,
                              void* d_out, int out_size, void* d_ws, size_t ws_size,
                              hipStream_t stream) {
    const float* costh = (const float*)d_in[0];
    const int*   label = (const int*)d_in[1];
    float* out = (float*)d_out;
    unsigned long long* slot = (unsigned long long*)d_ws;   // 512 qwords

    arc_fused<<<BATCH, BLOCK, 0, stream>>>(costh, label, out, slot);
}